// Round 1
// 727.071 us; speedup vs baseline: 1.0011x; 1.0011x over previous
//
#include <hip/hip_runtime.h>
#include <stdint.h>

// BiRNN on MI355X — round 8.
//  - r7 counters: scan = 360us, 4320 cy/step; on the 32 active CUs VALU~60%
//    (2600 cy/step) vs MFMA~23% (1010 cy) -> epilogue VALU is the step
//    ceiling, MFMA per-SIMD is structure-fixed (8 MFMAs/wave).
//  - r8: 64 fwd blocks x 8 batches, batch columns DUPLICATED into MFMA
//    N-slots 8..15 (B-frags + xg C-init read slot nn&7). Lanes nn and nn+8
//    hold identical accs; nn<8 finishes acc rows {0,1}, nn>=8 rows {2,3}.
//    Per-lane epilogue halves (1 packed pair, 16 trans vs 32); selection is
//    8 cndmask. MFMA cost/SIMD unchanged but spread over 2x CUs. h LDS
//    write shrinks to b16; B-reads become 2-lane broadcasts.
//  - Backward one-step fold moves to blocks 64..127 (128 blocks total).

typedef unsigned short u16;
typedef __bf16 bf16x8 __attribute__((ext_vector_type(8)));
typedef float  f32x4  __attribute__((ext_vector_type(4)));
typedef float  f32x2  __attribute__((ext_vector_type(2)));
typedef int    i32x4v __attribute__((ext_vector_type(4)));
typedef int    i32x8v __attribute__((ext_vector_type(8)));

#define B_    512
#define L_    200
#define EMB_  128
#define TDIM_ 10
#define IN_   138
#define INP_  160   // feat padded K (5 x 32)
#define H_    256
#define G4_   1024
#define T_    200
#define DS_   (1.0f/1024.0f)   // descale: (W*64)*(h*16), xg prescaled *1024
#define LOG2E 1.4426950408889634f
#define EXP2(x) __builtin_amdgcn_exp2f(x)
#define RCP(x)  __builtin_amdgcn_rcpf(x)

static __device__ __forceinline__ float bf2f(u16 u) {
  union { uint32_t i; float f; } v; v.i = ((uint32_t)u) << 16; return v.f;
}
static __device__ __forceinline__ u16 f2bf(float f) {
  __bf16 h = (__bf16)f; return __builtin_bit_cast(u16, h);
}
static __device__ __forceinline__ float bflo(uint32_t u) {
  return __builtin_bit_cast(float, (uint32_t)(u << 16));
}
static __device__ __forceinline__ float bfhi(uint32_t u) {
  return __builtin_bit_cast(float, (uint32_t)(u & 0xffff0000u));
}
static __device__ __forceinline__ float sigf(float x) {
  return RCP(1.0f + EXP2(-x * LOG2E));
}
static __device__ __forceinline__ float tanh_(float x) {
  x = fminf(fmaxf(x, -15.f), 15.f);
  float e = EXP2(2.0f * LOG2E * x);
  return (e - 1.0f) * RCP(e + 1.0f);
}
static __device__ __forceinline__ f32x4 mfma16(bf16x8 a, bf16x8 b, f32x4 c) {
  return __builtin_amdgcn_mfma_f32_16x16x32_bf16(a, b, c, 0, 0, 0);
}
static __device__ __forceinline__ f32x4 vzero4() {
  f32x4 v; v[0] = 0.f; v[1] = 0.f; v[2] = 0.f; v[3] = 0.f; return v;
}

// ---------------- K0b: W_hh fp32 -> K=128 MX A-frags, fp8 e4m3 *64 ---------
// UNCHANGED (layout validated). frag fs = w8*16 + tt8*2 + kp2,
// m-tile M = w8 + 8*tt8; lane(q,mm): A[g=(M)*16+mm][k=kp2*128+q*32+d*4+byte]
__global__ void k_prep_mx(const float* __restrict__ whh, int* __restrict__ wf8) {
  int idx = blockIdx.x * blockDim.x + threadIdx.x;  // < 65536 dwords
  int d = idx & 7;
  int lane = (idx >> 3) & 63;
  int fs = idx >> 9;
  int kp2 = fs & 1, tt = (fs >> 1) & 7, w = fs >> 4;
  int mm = lane & 15, q = lane >> 4;
  int g = (w + 8 * tt) * 16 + mm;
  int k = kp2 * 128 + q * 32 + d * 4;
  const float* src = whh + g * 256 + k;
  int v = __builtin_amdgcn_cvt_pk_fp8_f32(src[0] * 64.f, src[1] * 64.f, 0, false);
  v     = __builtin_amdgcn_cvt_pk_fp8_f32(src[2] * 64.f, src[3] * 64.f, v, true);
  wf8[idx] = v;
}

// ---------------- K2: norm + features fused (512 blocks, one per batch) -----
__global__ __launch_bounds__(256) void k_feat(
    const int* __restrict__ x, const float* __restrict__ emb,
    const float* __restrict__ tsW, u16* __restrict__ feat) {
  __shared__ float sh_t[224];
  __shared__ int   sh_id[224];
  __shared__ float sh_s[4];
  const int b = blockIdx.x, tid = threadIdx.x;
  float v = 0.f;
  if (tid < L_) {
    int2 p = *(const int2*)&x[(b * L_ + tid) * 2];
    float t = (float)p.x;
    sh_t[tid] = t;
    sh_id[tid] = p.y;
    v = t * t;
  }
  #pragma unroll
  for (int o = 32; o; o >>= 1) v += __shfl_down(v, o);
  if ((tid & 63) == 0) sh_s[tid >> 6] = v;
  __syncthreads();
  const float sq = sqrtf(sh_s[0] + sh_s[1] + sh_s[2] + sh_s[3]);
  for (int i = tid; i < L_ * INP_; i += 256) {
    int l = i / INP_, c = i - l * INP_;
    float v2 = 0.f;
    if (c < TDIM_) {
      float wd = tsW[c];
      float den = fmaxf(fabsf(wd) * sq, 1e-12f);
      v2 = sh_t[l] * wd * RCP(den);
    } else if (c < IN_) {
      int id = sh_id[l];
      float e = emb[(long)(id < 0 ? 0 : id) * EMB_ + (c - TDIM_)];
      v2 = (id >= 0) ? e : 0.f;
    }
    feat[(long)b * (L_ * INP_) + i] = f2bf(v2);
  }
}

// ---------------- K3: xg = (feat @ W_ih^T + b_ih + b_hh) * 1024, bf16 -------
// UNCHANGED (validated).
__global__ __launch_bounds__(512, 2) void k_xg(
    const u16* __restrict__ feat, const float* __restrict__ wih,
    const float* __restrict__ bih, const float* __restrict__ bhh,
    u16* __restrict__ xg) {
  __shared__ u16 Bs[256 * 176];
  const int nt = blockIdx.x;   // 0..3
  const int mt = blockIdx.y;   // 0..399
  const int tid = threadIdx.x;
  const int w = tid >> 6, lane = tid & 63;
  const int q = lane >> 4, nm = lane & 15;
  for (int i2 = tid; i2 < 256 * 88; i2 += 512) {
    int gl = i2 / 88, f2 = (i2 % 88) * 2;
    int pk = 0;
    if (f2 < IN_) {
      float2 v = *(const float2*)(wih + (long)(nt * 256 + gl) * IN_ + f2);
      pk = (int)f2bf(v.x) | ((int)f2bf(v.y) << 16);
    }
    *(int*)&Bs[gl * 176 + f2] = pk;
  }
  float bias[16];
  #pragma unroll
  for (int nu = 0; nu < 16; ++nu) {
    int g = nt * 256 + nu * 16 + nm;
    bias[nu] = bih[g] + bhh[g];
  }
  __syncthreads();
  f32x4 acc[2][16];
  #pragma unroll
  for (int m = 0; m < 2; ++m)
    #pragma unroll
    for (int nu = 0; nu < 16; ++nu) acc[m][nu] = vzero4();
  const u16* arow = feat + (long)(mt * 256 + w * 32) * INP_;
  #pragma unroll
  for (int kp = 0; kp < 5; ++kp) {
    bf16x8 a0 = *(const bf16x8*)(arow + (nm * INP_ + kp * 32 + q * 8));
    bf16x8 a1 = *(const bf16x8*)(arow + ((16 + nm) * INP_ + kp * 32 + q * 8));
    #pragma unroll
    for (int nu = 0; nu < 16; ++nu) {
      bf16x8 bb = *(const bf16x8*)&Bs[(nu * 16 + nm) * 176 + kp * 32 + q * 8];
      acc[0][nu] = mfma16(a0, bb, acc[0][nu]);
      acc[1][nu] = mfma16(a1, bb, acc[1][nu]);
    }
  }
  u16* Os = Bs;
  #pragma unroll
  for (int p = 0; p < 2; ++p) {
    __syncthreads();
    if ((w >> 2) == p) {
      #pragma unroll
      for (int nu = 0; nu < 16; ++nu)
        #pragma unroll
        for (int m = 0; m < 2; ++m)
          #pragma unroll
          for (int r = 0; r < 4; ++r) {
            int row = (w & 3) * 32 + m * 16 + 4 * q + r;
            Os[row * 264 + nu * 16 + nm] = f2bf((acc[m][nu][r] + bias[nu]) * 1024.f);
          }
    }
    __syncthreads();
    #pragma unroll
    for (int it = 0; it < 8; ++it) {
      int flat = it * 512 + tid;
      int row = flat >> 5, c = flat & 31;
      uint4 v = *(const uint4*)&Os[row * 264 + c * 8];
      *(uint4*)&xg[(long)(mt * 256 + p * 128 + row) * G4_ + nt * 256 + c * 8] = v;
    }
  }
}

// ---------------- K4: scan (blocks 0..63) + folded bwd (blocks 64..127) -----
#define F8MA(accv, Aa, Bv) \
  asm volatile("v_mfma_f32_16x16x128_f8f6f4 %0, %1, %2, %0" \
               : "+v"(accv) : "a"(Aa), "v"(Bv));
#define F8MV(accv, Av, Bv) \
  asm volatile("v_mfma_f32_16x16x128_f8f6f4 %0, %1, %2, %0" \
               : "+v"(accv) : "v"(Av), "v"(Bv));
#define AINIT(i) \
  f32x4 acc##i; acc##i[0] = bflo(pf##i.x); acc##i[1] = bfhi(pf##i.x); \
  acc##i[2] = bflo(pf##i.y); acc##i[3] = bfhi(pf##i.y);
#define PFL(i, ptr) pf##i = *(const uint2*)((ptr) + (16 * (w + 16 * (i)) + 4 * q));
// single packed-pair cell update; inputs are pre-selected f32x2 (i,f,g,o)
#define EPI(ai, af, ag, ao, cs2, hv2) f32x2 hv2; { \
  f32x2 xi = (ai) * c_sig, xf = (af) * c_sig, xo = (ao) * c_sig, xgv = (ag) * c_tg; \
  f32x2 ei, ef, eo, eg, ec; \
  ei[0] = EXP2(xi[0]); ei[1] = EXP2(xi[1]); \
  ef[0] = EXP2(xf[0]); ef[1] = EXP2(xf[1]); \
  eo[0] = EXP2(xo[0]); eo[1] = EXP2(xo[1]); \
  eg[0] = EXP2(xgv[0]); eg[1] = EXP2(xgv[1]); \
  f32x2 t1 = ef + 1.f; \
  f32x2 r1; r1[0] = RCP(t1[0]); r1[1] = RCP(t1[1]); \
  f32x2 t2 = (ei + 1.f) * (eg + 1.f); \
  f32x2 r2; r2[0] = RCP(t2[0]); r2[1] = RCP(t2[1]); \
  f32x2 c = cs2 * r1 + (eg - 1.f) * r2; \
  cs2 = c; \
  f32x2 xc = c * c_tc; \
  ec[0] = EXP2(xc[0]); ec[1] = EXP2(xc[1]); \
  f32x2 t3 = (eo + 1.f) * (ec + 1.f); \
  f32x2 r3; r3[0] = RCP(t3[0]); r3[1] = RCP(t3[1]); \
  hv2 = (ec * 16.f - 16.f) * r3; }   /* = h*16 for fp8 store */

#define FSOLD(M, kp2) (((M) & 7) * 16 + ((M) >> 3) * 2 + (kp2))
#define WLOAD(M, kp2) (*(const i32x8v*)(wf8 + ((long)(FSOLD(M, kp2)) * 64 + lane) * 8))

__global__ __launch_bounds__(1024, 4) void k_lstm_f(
    const int* __restrict__ wf8, const u16* __restrict__ xg,
    float* __restrict__ hf,
    const u16* __restrict__ feat, const float* __restrict__ wihb,
    const float* __restrict__ bihb, const float* __restrict__ bhhb,
    float* __restrict__ hb) {
  __shared__ i32x8v ldsW[32 * 64];   // 65536 B: tt=3 (o-gate) frags
  __shared__ int hls[2][16 * 68];    // 8704 B; fwd uses 8 slots, bwd reuses as fv

  if (blockIdx.x >= 64) {
    // ---- folded one-step backward LSTM (c0=0 -> forget gate dead) ----
    const int b0 = (blockIdx.x - 64) * 8;
    const int tid = threadIdx.x;   // 0..1023
    float* fv = (float*)hls;       // 1104 floats needed, 2176 available
    for (int i = tid; i < 8 * IN_; i += 1024) {
      int r = i / IN_, c = i - r * IN_;
      fv[r * IN_ + c] = bf2f(feat[((long)(b0 + r) * L_ + (L_ - 1)) * INP_ + c]);
    }
    __syncthreads();
    const int col = tid & 255, rq = tid >> 8;   // rows rq*2, rq*2+1
    float gi0 = bihb[col] + bhhb[col];
    float gg0 = bihb[512 + col] + bhhb[512 + col];
    float go0 = bihb[768 + col] + bhhb[768 + col];
    float gi1 = gi0, gg1 = gg0, go1 = go0;
    const float* wi_ = wihb + (long)col * IN_;
    const float* wg_ = wihb + (long)(512 + col) * IN_;
    const float* wo_ = wihb + (long)(768 + col) * IN_;
    const float* f0 = fv + (rq * 2) * IN_;
    const float* f1 = fv + (rq * 2 + 1) * IN_;
    for (int f = 0; f < IN_; ++f) {
      float a = wi_[f], g = wg_[f], o = wo_[f];
      float x0 = f0[f], x1 = f1[f];
      gi0 += a * x0; gi1 += a * x1;
      gg0 += g * x0; gg1 += g * x1;
      go0 += o * x0; go1 += o * x1;
    }
    float c0 = sigf(gi0) * tanh_(gg0);
    float c1 = sigf(gi1) * tanh_(gg1);
    hb[(long)(b0 + rq * 2) * H_ + col]     = sigf(go0) * tanh_(c0);
    hb[(long)(b0 + rq * 2 + 1) * H_ + col] = sigf(go1) * tanh_(c1);
    return;
  }

  // ---- forward scan: 64 blocks x 8 batches; wave w owns m-tiles {w+16*tt}.
  // Batch columns duplicated into N-slots 8..15: lane nn and nn+8 compute
  // identical accs for batch (nn&7); nn<8 finishes rows {0,1}, nn>=8 {2,3}.
  const int tid = threadIdx.x;
  const int w = tid >> 6;          // 0..15
  const int lane = tid & 63;
  const int q = lane >> 4;
  const int nn = lane & 15;
  const int sl = nn & 7;           // batch slot
  const int hi = (nn >> 3) & 1;    // 0: acc rows {0,1}; 1: acc rows {2,3}
  const int b = blockIdx.x * 8 + sl;
  const float c_sig = -DS_ * LOG2E;
  const float c_tg  = 2.f * DS_ * LOG2E;
  const float c_tc  = 2.f * LOG2E;

  // W frags: tt=0,1,2 (i,f,g) -> AGPR via "a" uses; tt=3 (o) -> LDS
  i32x8v A00 = WLOAD(w, 0),      A01 = WLOAD(w, 1);
  i32x8v A10 = WLOAD(w + 16, 0), A11 = WLOAD(w + 16, 1);
  i32x8v A20 = WLOAD(w + 32, 0), A21 = WLOAD(w + 32, 1);
  ldsW[(w * 2 + 0) * 64 + lane] = WLOAD(w + 48, 0);
  ldsW[(w * 2 + 1) * 64 + lane] = WLOAD(w + 48, 1);
  for (int i = tid; i < 16 * 68; i += 1024) hls[0][i] = 0;

  const u16* xgb = xg + (long)b * (L_ * G4_);
  uint2 pf0, pf1, pf2, pf3;
  PFL(0, xgb) PFL(1, xgb) PFL(2, xgb) PFL(3, xgb)
  f32x2 cs; cs[0] = 0.f; cs[1] = 0.f;
  __syncthreads();

  #pragma unroll 1
  for (int t = 0; t < T_; ++t) {
    const int* hr = hls[t & 1];
    i32x8v B0 = *(const i32x8v*)&hr[sl * 68 + q * 8];         // k 0..127
    i32x8v B1 = *(const i32x8v*)&hr[sl * 68 + 32 + q * 8];    // k 128..255
    i32x8v L0 = ldsW[(w * 2 + 0) * 64 + lane];
    i32x8v L1 = ldsW[(w * 2 + 1) * 64 + lane];
    AINIT(0) AINIT(1) AINIT(2) AINIT(3)
    {  // next step's xg prefetch; barrier is lgkm-only so it stays in flight
      const u16* xn = xgb + (long)(t + 1 < T_ ? t + 1 : t) * G4_;
      PFL(0, xn) PFL(1, xn) PFL(2, xn) PFL(3, xn)
    }
    F8MA(acc0, A00, B0) F8MA(acc1, A10, B0) F8MA(acc2, A20, B0) F8MV(acc3, L0, B0)
    F8MA(acc0, A01, B1) F8MA(acc1, A11, B1) F8MA(acc2, A21, B1) F8MV(acc3, L1, B1)
    asm volatile("s_nop 7\n\ts_nop 7"
                 : "+v"(acc0), "+v"(acc1), "+v"(acc2), "+v"(acc3));
    int* hw = hls[1 - (t & 1)];
    // select this lane's row pair (duplicated-column trick)
    f32x2 ai; ai[0] = hi ? acc0[2] : acc0[0]; ai[1] = hi ? acc0[3] : acc0[1];
    f32x2 af; af[0] = hi ? acc1[2] : acc1[0]; af[1] = hi ? acc1[3] : acc1[1];
    f32x2 ag; ag[0] = hi ? acc2[2] : acc2[0]; ag[1] = hi ? acc2[3] : acc2[1];
    f32x2 ao; ao[0] = hi ? acc3[2] : acc3[0]; ao[1] = hi ? acc3[3] : acc3[1];
    EPI(ai, af, ag, ao, cs, hv)   // rows {4q+2*hi, 4q+2*hi+1} of m-tile w
    int pk = __builtin_amdgcn_cvt_pk_fp8_f32(hv[0], hv[1], 0, false);
    ((unsigned short*)hw)[sl * 136 + 8 * w + 2 * q + hi] = (unsigned short)pk;
    if (t == T_ - 1) {
      f32x2 ov; ov[0] = hv[0] * 0.0625f; ov[1] = hv[1] * 0.0625f;
      *(f32x2*)&hf[(long)b * H_ + 16 * w + 4 * q + 2 * hi] = ov;
    }
    // raw barrier: wait DS only (lgkmcnt(0)); vmcnt prefetch NOT drained.
    __asm__ volatile("" ::: "memory");
    __builtin_amdgcn_s_waitcnt(0xc07f);
    __builtin_amdgcn_s_barrier();
    __asm__ volatile("" ::: "memory");
  }
}

// ---------------- K6: fc head ----------------
__global__ void k_fc(const float* __restrict__ hf, const float* __restrict__ hb,
                     const float* __restrict__ fcw, const float* __restrict__ fcb,
                     float* __restrict__ out) {
  int b = blockIdx.x;
  int lane = threadIdx.x;  // 64
  float p0 = 0.f, p1 = 0.f;
  #pragma unroll
  for (int k = lane; k < 2 * H_; k += 64) {
    float v = (k < H_) ? hf[b * H_ + k] : hb[b * H_ + (k - H_)];
    p0 += v * fcw[k];
    p1 += v * fcw[2 * H_ + k];
  }
  #pragma unroll
  for (int o = 32; o; o >>= 1) {
    p0 += __shfl_down(p0, o);
    p1 += __shfl_down(p1, o);
  }
  if (lane == 0) {
    out[b * 2 + 0] = p0 + fcb[0];
    out[b * 2 + 1] = p1 + fcb[1];
  }
}

extern "C" void kernel_launch(void* const* d_in, const int* in_sizes, int n_in,
                              void* d_out, int out_size, void* d_ws, size_t ws_size,
                              hipStream_t stream) {
  const int*   x    = (const int*)  d_in[0];
  const float* emb  = (const float*)d_in[1];
  const float* tsW  = (const float*)d_in[2];
  const float* wihf = (const float*)d_in[3];
  const float* whhf = (const float*)d_in[4];
  const float* bihf = (const float*)d_in[5];
  const float* bhhf = (const float*)d_in[6];
  const float* wihb = (const float*)d_in[7];
  // d_in[8] = w_hh_b: unused (one backward step from zero state)
  const float* bihb = (const float*)d_in[9];
  const float* bhhb = (const float*)d_in[10];
  const float* fcw  = (const float*)d_in[11];
  const float* fcb  = (const float*)d_in[12];
  float* out = (float*)d_out;

  // workspace layout (243,795,968 bytes total — proven to fit)
  char* ws = (char*)d_ws;
  int*   wf8  = (int*)  (ws + 2048);           //     262,144 (MX fp8 W frags)
  u16*   feat = (u16*)  (ws + 264192);         //  32,768,000
  u16*   xg   = (u16*)  (ws + 33032192);       // 209,715,200
  float* hf   = (float*)(ws + 242747392);      //     524,288
  float* hb   = (float*)(ws + 243271680);      //     524,288

  k_prep_mx<<<dim3(256),    dim3(256),  0, stream>>>(whhf, wf8);
  k_feat   <<<dim3(512),    dim3(256),  0, stream>>>(x, emb, tsW, feat);
  k_xg     <<<dim3(4, 400), dim3(512),  0, stream>>>(feat, wihf, bihf, bhhf, xg);
  k_lstm_f <<<dim3(128),    dim3(1024), 0, stream>>>(wf8, xg, hf,
                                                     feat, wihb, bihb, bhhb, hb);
  k_fc     <<<dim3(512),    dim3(64),   0, stream>>>(hf, hb, fcw, fcb, out);
}